// Round 1
// baseline (988.058 us; speedup 1.0000x reference)
//
#include <hip/hip_runtime.h>

// ATTNRNNAgent: B=4096, N=64, E=128, A=32, nh=8, e=32, HID=256, ATT=256, N_ACT=32
// Pipeline: K0 prep (bf16 weights + h0, mask-dtype detect) -> K1 fc1 -> K2 attn -> K3 GRU -> K4 out
// All GEMMs via v_mfma_f32_16x16x32_bf16 (A: row=l&15, k=(l>>4)*8+i ; B: col=l&15 same k ; D: col=l&15, row=(l>>4)*4+r)

using bfrag = __attribute__((ext_vector_type(8))) short;   // 8 bf16
using s4    = __attribute__((ext_vector_type(4))) short;   // 4 bf16
using ffrag = __attribute__((ext_vector_type(4))) float;   // 4 f32 acc

#define MFMA(a,b,c) __builtin_amdgcn_mfma_f32_16x16x32_bf16((a),(b),(c),0,0,0)
// XOR swizzle for row-major bf16 LDS tiles (16B granular), breaks power-of-2 row-stride conflicts
#define SWZ(row,col,S,xm) ((row)*(S) + ((((col)&~7) ^ (((row)&(xm))<<3)) | ((col)&7)))

// ws layout (in shorts)
#define OFF_FC1  128L
#define OFF_QW   32896L
#define OFF_KW   98432L
#define OFF_VW   163968L
#define OFF_WIH  229504L
#define OFF_WHH  426112L
#define OFF_OW   622720L
#define OFF_H0B  630912L
#define OFF_ATTB 34185344L
#define WS_NEED_BYTES 135479552L

__device__ inline unsigned short f2bf(float x){
  union { float f; unsigned u; } v; v.f = x;
  unsigned r = v.u + 0x7fffu + ((v.u >> 16) & 1u);   // RNE
  return (unsigned short)(r >> 16);
}
__device__ inline bool getmask(const void* p, long i, int byteflag){
  return byteflag ? (((const unsigned char*)p)[i] != 0)
                  : (((const int*)p)[i] != 0);
}
__device__ inline ffrag fzero(){ ffrag z; z[0]=0.f; z[1]=0.f; z[2]=0.f; z[3]=0.f; return z; }

// ---------------- K0: weight/h0 -> bf16, detect mask dtype ----------------
__global__ void k0_prep(const float* __restrict__ fc1, const float* __restrict__ qw,
    const float* __restrict__ kw, const float* __restrict__ vw, const float* __restrict__ wih,
    const float* __restrict__ whh, const float* __restrict__ ow, const float* __restrict__ h0,
    const void* __restrict__ obsm, short* __restrict__ ws){
  long tid = (long)blockIdx.x*blockDim.x + threadIdx.x;
  long n = (long)gridDim.x*blockDim.x;
  if (tid == 0){
    // byte-bool masks: first 256 int32 views are ~never all in {0,1}; int32 masks: always are.
    const int* mi = (const int*)obsm;
    int f = 0;
    for (int i=0;i<256;i++){ if ((unsigned)mi[i] > 1u){ f = 1; break; } }
    ((int*)ws)[0] = f;
  }
  for (long i=tid; i<32768; i+=n) ws[OFF_FC1+i] = (short)f2bf(fc1[i]);
  for (long i=tid; i<65536; i+=n){
    ws[OFF_QW+i] = (short)f2bf(qw[i]);
    ws[OFF_KW+i] = (short)f2bf(kw[i]);
    ws[OFF_VW+i] = (short)f2bf(vw[i]);
  }
  for (long i=tid; i<196608; i+=n){
    ws[OFF_WIH+i] = (short)f2bf(wih[i]);
    ws[OFF_WHH+i] = (short)f2bf(whh[i]);
  }
  for (long i=tid; i<8192; i+=n) ws[OFF_OW+i] = (short)f2bf(ow[i]);
  for (long i=tid; i<33554432L; i+=n) ws[OFF_H0B+i] = (short)f2bf(h0[i]);
}

// ---------------- K1: x = relu(inp @ fc1_w^T + b) -> xB (bf16) ----------------
// M=262144 (128/block), N=256, K=128
__global__ __launch_bounds__(512) void k1_fc1(const float* __restrict__ inp,
    const float* __restrict__ fc1_b, const short* __restrict__ wsw, short* __restrict__ xB){
  __shared__ __align__(16) short a_s[128*128];
  __shared__ __align__(16) short w_s[256*128];
  int t = threadIdx.x; long R0 = (long)blockIdx.x * 128;
  for (int i=0;i<4;i++){                       // stage A (fp32 -> bf16)
    int c = t + i*512; int row = c >> 4; int cc = (c & 15)*8;
    const float* src = inp + (R0 + row)*128 + cc;
    float4 f0 = *(const float4*)src; float4 f1 = *(const float4*)(src + 4);
    bfrag v8;
    v8[0]=(short)f2bf(f0.x); v8[1]=(short)f2bf(f0.y); v8[2]=(short)f2bf(f0.z); v8[3]=(short)f2bf(f0.w);
    v8[4]=(short)f2bf(f1.x); v8[5]=(short)f2bf(f1.y); v8[6]=(short)f2bf(f1.z); v8[7]=(short)f2bf(f1.w);
    *(bfrag*)(a_s + SWZ(row, cc, 128, 7)) = v8;
  }
  for (int i=0;i<8;i++){                       // stage W (bf16 from ws)
    int c = t + i*512; int row = c >> 4; int cc = (c & 15)*8;
    *(bfrag*)(w_s + SWZ(row, cc, 128, 7)) = *(const bfrag*)(wsw + row*128 + cc);
  }
  __syncthreads();
  int lane = t & 63, w = t >> 6, lr = lane & 15, ko = lane >> 4;
  ffrag acc[16];
  for (int i=0;i<16;i++) acc[i] = fzero();
  for (int ks=0; ks<4; ks++){
    int kc = ks*32 + ko*8;
    bfrag a = *(const bfrag*)(a_s + SWZ(w*16+lr, kc, 128, 7));
    for (int nt=0; nt<16; nt++){
      bfrag bb = *(const bfrag*)(w_s + SWZ(nt*16+lr, kc, 128, 7));
      acc[nt] = MFMA(a, bb, acc[nt]);
    }
  }
  for (int nt=0; nt<16; nt++){
    float bias = fc1_b[nt*16 + lr];
    for (int r=0;r<4;r++){
      int row = w*16 + ko*4 + r;
      float v = acc[nt][r] + bias;
      v = v > 0.f ? v : 0.f;
      xB[(R0 + row)*256 + nt*16 + lr] = (short)f2bf(v);
    }
  }
}

// ---------------- K2: per-batch attention (q/k/v + masked softmax + PV) ----------------
__global__ __launch_bounds__(512) void k2_attn(const short* __restrict__ xB,
    const short* __restrict__ wq, const short* __restrict__ wk, const short* __restrict__ wv,
    const float* __restrict__ qb, const float* __restrict__ kb, const float* __restrict__ vb,
    const void* __restrict__ obsm, short* __restrict__ attB, const int* __restrict__ flagp){
  __shared__ __align__(16) short x_s[64*256];     // x[b] tile
  __shared__ __align__(16) short hw_s[3*32*256];  // per-head q/k/v weight slabs
  __shared__ __align__(16) short q_s[32*32];
  __shared__ __align__(16) short k_s[64*32];
  __shared__ __align__(16) short vT_s[32*64];     // v transposed [e][n]
  __shared__ __align__(16) short p_s[32*64];      // unnormalized exp probs (bf16)
  __shared__ float s_s[32*68];                    // raw scores
  __shared__ float rs_s[32];                      // 1/rowsum (0 if all-masked)
  int t = threadIdx.x; int b = blockIdx.x;
  int lane = t&63, w = t>>6, lr = lane&15, ko = lane>>4;
  int mflag = *flagp;
  for (int i=0;i<4;i++){                          // stage x[b]
    int c = t + i*512; int row = c>>5; int cc = (c&31)*8;
    *(bfrag*)(x_s + SWZ(row, cc, 256, 7)) = *(const bfrag*)(xB + ((long)b*64+row)*256 + cc);
  }
  for (int h=0; h<8; h++){
    __syncthreads();                              // protect prev head's p_s/vT_s/rs_s
    for (int i=0;i<6;i++){                        // stage head weights (3 x 32 x 256)
      int c = t + i*512;
      int m = c >> 10; int cm = c & 1023; int row = cm>>5; int cc = (cm&31)*8;
      const short* src = (m==0?wq:(m==1?wk:wv)) + ((h*32+row)*256 + cc);
      *(bfrag*)(hw_s + m*8192 + SWZ(row, cc, 256, 7)) = *(const bfrag*)src;
    }
    __syncthreads();
    // q (4 tiles), k (8), v (8) distributed over 8 waves
    for (int idx = w; idx < 20; idx += 8){
      int kind, mt, nt;
      if (idx < 4){ kind=0; mt=idx>>1; nt=idx&1; }
      else if (idx < 12){ kind=1; int j=idx-4; mt=j>>1; nt=j&1; }
      else { kind=2; int j=idx-12; mt=j>>1; nt=j&1; }
      const short* slab = hw_s + kind*8192;
      ffrag acc = fzero();
      for (int ks=0; ks<8; ks++){
        int kc = ks*32 + ko*8;
        bfrag a  = *(const bfrag*)(x_s + SWZ(mt*16+lr, kc, 256, 7));
        bfrag bb = *(const bfrag*)(slab + SWZ(nt*16+lr, kc, 256, 7));
        acc = MFMA(a, bb, acc);
      }
      float bias = (kind==0?qb:(kind==1?kb:vb))[h*32 + nt*16 + lr];
      for (int r=0;r<4;r++){
        float val = acc[r] + bias;
        int orow = mt*16 + ko*4 + r, ocol = nt*16 + lr;
        if (kind==0)      q_s[SWZ(orow, ocol, 32, 3)] = (short)f2bf(val);
        else if (kind==1) k_s[SWZ(orow, ocol, 32, 3)] = (short)f2bf(val);
        else { val = val>0.f?val:0.f; vT_s[SWZ(ocol, orow, 64, 7)] = (short)f2bf(val); }
      }
    }
    __syncthreads();
    {   // score = q @ k^T : 8 tiles (2m x 4n), one per wave
      int mt = w>>2, nt = w&3;
      bfrag a  = *(const bfrag*)(q_s + SWZ(mt*16+lr, ko*8, 32, 3));
      bfrag bb = *(const bfrag*)(k_s + SWZ(nt*16+lr, ko*8, 32, 3));
      ffrag acc = fzero();
      acc = MFMA(a, bb, acc);
      for (int r=0;r<4;r++) s_s[(mt*16+ko*4+r)*68 + nt*16+lr] = acc[r];
    }
    __syncthreads();
    {   // masked softmax over 64 cols: 16 threads per row, 4 cols each
      int row = t >> 4, sub = t & 15, n0 = sub*4;
      const float scale = 0.17677669529663687f;   // 1/sqrt(32)
      long mbase = (long)b*4096 + (long)row*64 + n0;
      float sv[4]; int mk[4];
      for (int i=0;i<4;i++){
        mk[i] = getmask(obsm, mbase+i, mflag) ? 1 : 0;
        sv[i] = s_s[row*68 + n0 + i] * scale;
      }
      float mx = -3e38f;
      for (int i=0;i<4;i++) if (!mk[i]) mx = fmaxf(mx, sv[i]);
      for (int d=1; d<16; d<<=1) mx = fmaxf(mx, __shfl_xor(mx, d));
      float pv[4]; float sum = 0.f;
      for (int i=0;i<4;i++){ pv[i] = mk[i] ? 0.f : __expf(sv[i]-mx); sum += pv[i]; }
      for (int d=1; d<16; d<<=1) sum += __shfl_xor(sum, d);
      if (sub==0) rs_s[row] = (sum > 0.f) ? (1.f/sum) : 0.f;  // all-masked row -> att 0
      s4 pb;
      for (int i=0;i<4;i++) pb[i] = (short)f2bf(pv[i]);
      *(s4*)(p_s + SWZ(row, n0, 64, 7)) = pb;
    }
    __syncthreads();
    if (w < 4){   // att = (p @ v) * rs : 4 tiles
      int mt = w>>1, nt = w&1;
      ffrag acc = fzero();
      for (int ksr=0; ksr<2; ksr++){
        int kc = ksr*32 + ko*8;
        bfrag a  = *(const bfrag*)(p_s + SWZ(mt*16+lr, kc, 64, 7));
        bfrag bb = *(const bfrag*)(vT_s + SWZ(nt*16+lr, kc, 64, 7));
        acc = MFMA(a, bb, acc);
      }
      for (int r=0;r<4;r++){
        int arow = mt*16 + ko*4 + r;
        float val = acc[r] * rs_s[arow];
        attB[((long)b*32 + arow)*256 + h*32 + nt*16 + lr] = (short)f2bf(val);
      }
    }
  }
}

// ---------------- K3: GRU cell (gi = att@w_ih^T, gh = h0@w_hh^T, gates, h) ----------------
// grid = 1024 m-blocks (128 rows) x 8 j-blocks (32 gate cols)
__global__ __launch_bounds__(512) void k3_gru(const short* __restrict__ attB,
    const short* __restrict__ h0B, const short* __restrict__ wih, const short* __restrict__ whh,
    const float* __restrict__ h0f, const float* __restrict__ b_ih, const float* __restrict__ b_hh,
    const void* __restrict__ scen, float* __restrict__ hout, const int* __restrict__ flagp){
  __shared__ __align__(16) short wih_s[3*32*256];
  __shared__ __align__(16) short whh_s[3*32*256];
  int t = threadIdx.x;
  int mblk = blockIdx.x >> 3, jblk = blockIdx.x & 7;
  long R0 = (long)mblk * 128; int j0 = jblk*32;
  int mflag = *flagp;
  for (int i=0;i<12;i++){   // stage 6 slabs of 32x256 (r,z,n gate rows for this j-chunk)
    int c = t + i*512;
    int slab = c >> 10; int cm = c & 1023; int row = cm >> 5; int cc = (cm & 31)*8;
    const short* src; short* dst;
    if (slab < 3){ src = wih + (((long)slab*256 + j0 + row)*256 + cc); dst = wih_s + slab*8192; }
    else         { src = whh + (((long)(slab-3)*256 + j0 + row)*256 + cc); dst = whh_s + (slab-3)*8192; }
    *(bfrag*)(dst + SWZ(row, cc, 256, 7)) = *(const bfrag*)src;
  }
  __syncthreads();
  int lane = t & 63, w = t >> 6, lr = lane & 15, ko = lane >> 4;
  long abase = (R0 + w*16 + lr) * 256L;
  ffrag acc[6][2];
  for (int g=0;g<6;g++) for (int nt=0;nt<2;nt++) acc[g][nt] = fzero();
  bfrag a_att = *(const bfrag*)(attB + abase + ko*8);
  bfrag a_h0  = *(const bfrag*)(h0B  + abase + ko*8);
  for (int ks=0; ks<8; ks++){
    bfrag n_att = a_att, n_h0 = a_h0;
    if (ks < 7){   // 1-deep prefetch of next K-step A-frags
      int kc = (ks+1)*32 + ko*8;
      n_att = *(const bfrag*)(attB + abase + kc);
      n_h0  = *(const bfrag*)(h0B  + abase + kc);
    }
    int kc = ks*32 + ko*8;
    for (int g=0; g<3; g++){
      for (int nt=0; nt<2; nt++){
        bfrag bi = *(const bfrag*)(wih_s + g*8192 + SWZ(nt*16+lr, kc, 256, 7));
        acc[g][nt] = MFMA(a_att, bi, acc[g][nt]);
      }
      for (int nt=0; nt<2; nt++){
        bfrag bh = *(const bfrag*)(whh_s + g*8192 + SWZ(nt*16+lr, kc, 256, 7));
        acc[3+g][nt] = MFMA(a_h0, bh, acc[3+g][nt]);
      }
    }
    a_att = n_att; a_h0 = n_h0;
  }
  for (int nt=0; nt<2; nt++){
    int j = j0 + nt*16 + lr;
    float bir = b_ih[j],     bhr = b_hh[j];
    float biz = b_ih[256+j], bhz = b_hh[256+j];
    float bin = b_ih[512+j], bhn = b_hh[512+j];
    for (int r=0;r<4;r++){
      long row = R0 + w*16 + ko*4 + r;
      float ir = acc[0][nt][r], iz = acc[1][nt][r], inn = acc[2][nt][r];
      float hr = acc[3][nt][r], hz = acc[4][nt][r], hn = acc[5][nt][r];
      float rr = 1.f/(1.f + __expf(-(ir + hr + bir + bhr)));
      float zz = 1.f/(1.f + __expf(-(iz + hz + biz + bhz)));
      float ag = inn + bin + rr*(hn + bhn);
      float nn = 2.f/(1.f + __expf(-2.f*ag)) - 1.f;   // tanh
      float h0v = h0f[row*256 + j];
      float hv = (1.f - zz)*nn + zz*h0v;
      if (getmask(scen, row, mflag)) hv = 0.f;
      hout[row*256 + j] = hv;
    }
  }
}

// ---------------- K4: q_out = h @ out_w^T + out_b (masked) ----------------
__global__ __launch_bounds__(512) void k4_out(const float* __restrict__ hout,
    const short* __restrict__ ow, const float* __restrict__ out_b,
    const void* __restrict__ scen, float* __restrict__ qout, const int* __restrict__ flagp){
  __shared__ __align__(16) short ow_s[32*256];
  int t = threadIdx.x; long R0 = (long)blockIdx.x * 256;
  int mflag = *flagp;
  for (int i=0;i<2;i++){
    int c = t + i*512; int row = c >> 5; int cc = (c & 31)*8;
    *(bfrag*)(ow_s + SWZ(row, cc, 256, 7)) = *(const bfrag*)(ow + row*256 + cc);
  }
  __syncthreads();
  int lane = t&63, w = t>>6, lr = lane&15, ko = lane>>4;
  ffrag acc[2][2];
  for (int a=0;a<2;a++) for (int bq=0;bq<2;bq++) acc[a][bq]=fzero();
  for (int ks=0; ks<8; ks++){
    int kc = ks*32 + ko*8;
    for (int mi=0; mi<2; mi++){
      long row = R0 + (w*2+mi)*16 + lr;
      const float* hp = hout + row*256 + kc;
      float4 f0 = *(const float4*)hp; float4 f1 = *(const float4*)(hp+4);
      bfrag a;
      a[0]=(short)f2bf(f0.x); a[1]=(short)f2bf(f0.y); a[2]=(short)f2bf(f0.z); a[3]=(short)f2bf(f0.w);
      a[4]=(short)f2bf(f1.x); a[5]=(short)f2bf(f1.y); a[6]=(short)f2bf(f1.z); a[7]=(short)f2bf(f1.w);
      for (int nt=0; nt<2; nt++){
        bfrag bb = *(const bfrag*)(ow_s + SWZ(nt*16+lr, kc, 256, 7));
        acc[mi][nt] = MFMA(a, bb, acc[mi][nt]);
      }
    }
  }
  for (int mi=0;mi<2;mi++) for (int nt=0;nt<2;nt++){
    int col = nt*16 + lr;
    float ob = out_b[col];
    for (int r=0;r<4;r++){
      long row = R0 + (w*2+mi)*16 + ko*4 + r;
      float qv = acc[mi][nt][r] + ob;
      if (getmask(scen, row, mflag)) qv = 0.f;
      qout[row*32 + col] = qv;
    }
  }
}

extern "C" void kernel_launch(void* const* d_in, const int* in_sizes, int n_in,
                              void* d_out, int out_size, void* d_ws, size_t ws_size,
                              hipStream_t stream){
  const float* inputs = (const float*)d_in[0];
  const float* hidden = (const float*)d_in[1];
  const float* fc1_w  = (const float*)d_in[2];
  const float* fc1_b  = (const float*)d_in[3];
  const float* q_w    = (const float*)d_in[4];
  const float* q_b    = (const float*)d_in[5];
  const float* k_w    = (const float*)d_in[6];
  const float* k_b    = (const float*)d_in[7];
  const float* v_w    = (const float*)d_in[8];
  const float* v_b    = (const float*)d_in[9];
  const float* w_ih   = (const float*)d_in[10];
  const float* w_hh   = (const float*)d_in[11];
  const float* b_ih   = (const float*)d_in[12];
  const float* b_hh   = (const float*)d_in[13];
  const float* out_w  = (const float*)d_in[14];
  const float* out_b  = (const float*)d_in[15];
  const void* obsm    = d_in[16];
  const void* scen    = d_in[17];
  (void)in_sizes; (void)n_in; (void)out_size;
  if ((long)ws_size < WS_NEED_BYTES) return;   // can't run without scratch
  short* ws = (short*)d_ws;
  const int* flagp = (const int*)d_ws;
  float* qout = (float*)d_out;
  float* hout = qout + 4194304;                // h region (overwritten by K3)
  short* xB   = (short*)hout;                  // x (bf16) borrows h region until K3
  short* attB = ws + OFF_ATTB;
  short* h0B  = ws + OFF_H0B;

  hipLaunchKernelGGL(k0_prep, dim3(4096), dim3(256), 0, stream,
      fc1_w, q_w, k_w, v_w, w_ih, w_hh, out_w, hidden, obsm, ws);
  hipLaunchKernelGGL(k1_fc1, dim3(2048), dim3(512), 0, stream,
      inputs, fc1_b, ws + OFF_FC1, xB);
  hipLaunchKernelGGL(k2_attn, dim3(4096), dim3(512), 0, stream,
      xB, ws + OFF_QW, ws + OFF_KW, ws + OFF_VW, q_b, k_b, v_b, obsm, attB, flagp);
  hipLaunchKernelGGL(k3_gru, dim3(8192), dim3(512), 0, stream,
      attB, h0B, ws + OFF_WIH, ws + OFF_WHH, hidden, b_ih, b_hh, scen, hout, flagp);
  hipLaunchKernelGGL(k4_out, dim3(512), dim3(512), 0, stream,
      hout, ws + OFF_OW, out_b, scen, qout, flagp);
}

// Round 2
// 780.161 us; speedup vs baseline: 1.2665x; 1.2665x over previous
//
#include <hip/hip_runtime.h>

// ATTNRNNAgent: B=4096, N=64, E=128, A=32, nh=8, e=32, HID=256, ATT=256, N_ACT=32
// K0 prep -> 4x( k1_fqkv chunk, k2_attn chunk ) -> K3 GRU -> K4 out
// All GEMMs via v_mfma_f32_16x16x32_bf16
//   A-frag: row=lane&15, k=(lane>>4)*8+i ; B-frag: col=lane&15 same k
//   D-frag: col=lane&15, row=(lane>>4)*4+r

using bfrag = __attribute__((ext_vector_type(8))) short;   // 8 bf16
using ffrag = __attribute__((ext_vector_type(4))) float;   // 4 f32 acc

#define MFMA(a,b,c) __builtin_amdgcn_mfma_f32_16x16x32_bf16((a),(b),(c),0,0,0)
// XOR swizzle for row-major bf16 LDS tiles (16B granular)
#define SWZ(row,col,S,xm) ((row)*(S) + ((((col)&~7) ^ (((row)&(xm))<<3)) | ((col)&7)))

// ws layout (in shorts)
#define OFF_FC1  128L
#define OFF_QW   32896L
#define OFF_KW   98432L
#define OFF_VW   163968L
#define OFF_WIH  229504L
#define OFF_WHH  426112L
#define OFF_OW   622720L
#define OFF_H0B  630912L
#define OFF_ATTB 34185344L
#define WS_NEED_BYTES 135479552L

__device__ inline unsigned short f2bf(float x){
  union { float f; unsigned u; } v; v.f = x;
  unsigned r = v.u + 0x7fffu + ((v.u >> 16) & 1u);   // RNE
  return (unsigned short)(r >> 16);
}
__device__ inline bool getmask(const void* p, long i, int byteflag){
  return byteflag ? (((const unsigned char*)p)[i] != 0)
                  : (((const int*)p)[i] != 0);
}
__device__ inline ffrag fzero(){ ffrag z; z[0]=0.f; z[1]=0.f; z[2]=0.f; z[3]=0.f; return z; }

// ---------------- K0: weights/h0 -> bf16, detect mask dtype ----------------
__global__ void k0_prep(const float* __restrict__ fc1, const float* __restrict__ qw,
    const float* __restrict__ kw, const float* __restrict__ vw, const float* __restrict__ wih,
    const float* __restrict__ whh, const float* __restrict__ ow, const float* __restrict__ h0,
    const void* __restrict__ obsm, short* __restrict__ ws){
  long tid = (long)blockIdx.x*blockDim.x + threadIdx.x;
  long n = (long)gridDim.x*blockDim.x;
  if (tid == 0){
    const int* mi = (const int*)obsm;
    int f = 0;
    for (int i=0;i<256;i++){ if ((unsigned)mi[i] > 1u){ f = 1; break; } }
    ((int*)ws)[0] = f;
  }
  for (long i=tid; i<32768; i+=n) ws[OFF_FC1+i] = (short)f2bf(fc1[i]);
  for (long i=tid; i<65536; i+=n){
    ws[OFF_QW+i] = (short)f2bf(qw[i]);
    ws[OFF_KW+i] = (short)f2bf(kw[i]);
    ws[OFF_VW+i] = (short)f2bf(vw[i]);
  }
  for (long i=tid; i<196608; i+=n){
    ws[OFF_WIH+i] = (short)f2bf(wih[i]);
    ws[OFF_WHH+i] = (short)f2bf(whh[i]);
  }
  for (long i=tid; i<8192; i+=n) ws[OFF_OW+i] = (short)f2bf(ow[i]);
  for (long i=tid; i<33554432L; i+=n) ws[OFF_H0B+i] = (short)f2bf(h0[i]);
}

// ---------------- K1': fused fc1 + QKV projection (per 65536-row chunk) ----------------
// phase1: x = relu(inp@fc1^T+b) for 128 rows -> regs -> x_s (LDS)
// phase2: 6 segments (kind q/k/v x N-half): out = x @ W_half^T + bias
__global__ __launch_bounds__(512) void k1_fqkv(const float* __restrict__ inp,
    const short* __restrict__ fc1B, const float* __restrict__ fc1_b,
    const short* __restrict__ wq, const short* __restrict__ wk, const short* __restrict__ wv,
    const float* __restrict__ qb, const float* __restrict__ kb, const float* __restrict__ vb,
    short* __restrict__ qC, short* __restrict__ kC, short* __restrict__ vC, int chunkB){
  __shared__ __align__(16) short smem[65536];   // 128 KB
  short* a_s  = smem;            // phase1 A: 128x128
  short* fw_s = smem + 16384;    // phase1 W: 256x128
  short* x_s  = smem;            // phase2 X: 128x256
  short* wh_s = smem + 32768;    // phase2 W-half: 128x256
  int t = threadIdx.x;
  long R0 = (long)blockIdx.x * 128;            // chunk-local row base
  long gRow0 = (long)chunkB*65536 + R0;        // global input row base
  int lane = t&63, w = t>>6, lr = lane&15, ko = lane>>4;
  // ---- phase1 staging ----
  for (int i=0;i<4;i++){
    int c = t + i*512; int row = c>>4; int cc = (c&15)*8;
    const float* src = inp + (gRow0 + row)*128 + cc;
    float4 f0 = *(const float4*)src; float4 f1 = *(const float4*)(src+4);
    bfrag v8;
    v8[0]=(short)f2bf(f0.x); v8[1]=(short)f2bf(f0.y); v8[2]=(short)f2bf(f0.z); v8[3]=(short)f2bf(f0.w);
    v8[4]=(short)f2bf(f1.x); v8[5]=(short)f2bf(f1.y); v8[6]=(short)f2bf(f1.z); v8[7]=(short)f2bf(f1.w);
    *(bfrag*)(a_s + SWZ(row, cc, 128, 7)) = v8;
  }
  for (int i=0;i<8;i++){
    int c = t + i*512; int row = c>>4; int cc = (c&15)*8;
    *(bfrag*)(fw_s + SWZ(row, cc, 128, 7)) = *(const bfrag*)(fc1B + row*128 + cc);
  }
  __syncthreads();
  // ---- phase1 MFMA: x-tile (128x256) ----
  ffrag acc1[16];
  #pragma unroll
  for (int i=0;i<16;i++) acc1[i]=fzero();
  for (int ks=0; ks<4; ks++){
    int kc = ks*32 + ko*8;
    bfrag a = *(const bfrag*)(a_s + SWZ(w*16+lr, kc, 128, 7));
    #pragma unroll
    for (int nt=0; nt<16; nt++){
      bfrag bb = *(const bfrag*)(fw_s + SWZ(nt*16+lr, kc, 128, 7));
      acc1[nt] = MFMA(a, bb, acc1[nt]);
    }
  }
  __syncthreads();   // all phase1 LDS reads complete -> reuse smem
  // write x (bias+relu, bf16) into x_s (wave writes only its own 16 rows)
  #pragma unroll
  for (int nt=0; nt<16; nt++){
    float bias = fc1_b[nt*16+lr];
    #pragma unroll
    for (int r=0;r<4;r++){
      int row = w*16 + ko*4 + r;
      float v = acc1[nt][r] + bias; v = v>0.f?v:0.f;
      x_s[SWZ(row, nt*16+lr, 256, 7)] = (short)f2bf(v);
    }
  }
  // preload own A-frags (wave-private rows -> no barrier needed)
  bfrag a_r[8];
  #pragma unroll
  for (int ks=0; ks<8; ks++)
    a_r[ks] = *(const bfrag*)(x_s + SWZ(w*16+lr, ks*32+ko*8, 256, 7));
  // ---- phase2: 6 segments ----
  for (int seg=0; seg<6; seg++){
    int kind = seg>>1, half = seg&1;
    const short* wsrc = (kind==0?wq:(kind==1?wk:wv)) + half*32768;
    for (int i=0;i<8;i++){
      int c = t + i*512; int row = c>>5; int cc = (c&31)*8;
      *(bfrag*)(wh_s + SWZ(row, cc, 256, 7)) = *(const bfrag*)(wsrc + row*256 + cc);
    }
    __syncthreads();
    ffrag acc2[8];
    #pragma unroll
    for (int i=0;i<8;i++) acc2[i]=fzero();
    for (int ks=0; ks<8; ks++){
      int kc = ks*32 + ko*8;
      #pragma unroll
      for (int nt=0; nt<8; nt++){
        bfrag bb = *(const bfrag*)(wh_s + SWZ(nt*16+lr, kc, 256, 7));
        acc2[nt] = MFMA(a_r[ks], bb, acc2[nt]);
      }
    }
    const float* bsrc = (kind==0?qb:(kind==1?kb:vb));
    #pragma unroll
    for (int nt=0; nt<8; nt++){
      int col = half*128 + nt*16 + lr;
      float bias = bsrc[col];
      #pragma unroll
      for (int r=0;r<4;r++){
        int row = w*16 + ko*4 + r;
        long rl = R0 + row;
        float v = acc2[nt][r] + bias;
        if (kind==0){
          if ((row&32)==0){                       // q: only agent rows n<32
            long qrow = ((rl>>6)<<5) + (row&31);
            qC[qrow*256 + col] = (short)f2bf(v);
          }
        } else if (kind==1){
          kC[rl*256 + col] = (short)f2bf(v);
        } else {
          v = v>0.f?v:0.f;
          vC[rl*256 + col] = (short)f2bf(v);
        }
      }
    }
    __syncthreads();   // protect wh_s restage
  }
}

// ---------------- K2: attention, one wave per (b,head) ----------------
__global__ __launch_bounds__(512,4) void k2_attn(const short* __restrict__ qC,
    const short* __restrict__ kC, const short* __restrict__ vC,
    const void* __restrict__ obsm, short* __restrict__ attB,
    const int* __restrict__ flagp, int chunkB){
  __shared__ __align__(16) short vT_s[8][2048];   // per-wave v^T [e=32][n=64]
  __shared__ __align__(16) short p_s[8][2048];    // per-wave p   [a=32][n=64]
  __shared__ unsigned char m_s[2048];             // obs_mask rows 0..31
  int t = threadIdx.x, bl = blockIdx.x;
  long b = (long)chunkB*1024 + bl;
  int lane = t&63, w = t>>6, lr = lane&15, ko = lane>>4;
  int mflag = *flagp;
  if (mflag){
    uchar4 mv = *(const uchar4*)((const unsigned char*)obsm + b*4096 + t*4);
    m_s[t*4]=mv.x; m_s[t*4+1]=mv.y; m_s[t*4+2]=mv.z; m_s[t*4+3]=mv.w;
  } else {
    int4 mv = *(const int4*)((const int*)obsm + b*4096 + t*4);
    m_s[t*4]  =(unsigned char)(mv.x!=0); m_s[t*4+1]=(unsigned char)(mv.y!=0);
    m_s[t*4+2]=(unsigned char)(mv.z!=0); m_s[t*4+3]=(unsigned char)(mv.w!=0);
  }
  const int h = w;
  // q/k fragments straight from global (coalesced 16B/lane)
  const short* qh = qC + ((long)bl*32)*256 + h*32 + ko*8;
  bfrag a_q[2];
  #pragma unroll
  for (int mt=0; mt<2; mt++) a_q[mt] = *(const bfrag*)(qh + (mt*16+lr)*256);
  const short* kh = kC + ((long)bl*64)*256 + h*32 + ko*8;
  bfrag b_k[4];
  #pragma unroll
  for (int nt=0; nt<4; nt++) b_k[nt] = *(const bfrag*)(kh + (nt*16+lr)*256);
  // stage v transposed into per-wave LDS
  #pragma unroll
  for (int i=0;i<4;i++){
    int n = i*16 + (lane>>2); int e0 = (lane&3)*8;
    bfrag vv = *(const bfrag*)(vC + ((long)bl*64 + n)*256 + h*32 + e0);
    #pragma unroll
    for (int j=0;j<8;j++) vT_s[w][SWZ(e0+j, n, 64, 7)] = vv[j];
  }
  // score = q@k^T (8 MFMAs)
  ffrag sc[2][4];
  #pragma unroll
  for (int mt=0; mt<2; mt++)
    #pragma unroll
    for (int nt=0; nt<4; nt++) sc[mt][nt] = MFMA(a_q[mt], b_k[nt], fzero());
  __syncthreads();   // m_s ready (vT/p are wave-private)
  // masked softmax fully in registers (rows live in this lane's 16-lane group)
  const float scale = 0.17677669529663687f;   // 1/sqrt(32)
  float rsi[2][4];
  #pragma unroll
  for (int mt=0; mt<2; mt++){
    #pragma unroll
    for (int r=0; r<4; r++){
      int arow = mt*16 + ko*4 + r;
      float sv[4]; int mk[4];
      #pragma unroll
      for (int nt=0; nt<4; nt++){
        mk[nt] = m_s[arow*64 + nt*16 + lr];
        sv[nt] = sc[mt][nt][r] * scale;
      }
      float mx = -3.0e38f;
      #pragma unroll
      for (int nt=0; nt<4; nt++) if (!mk[nt]) mx = fmaxf(mx, sv[nt]);
      for (int d=1; d<16; d<<=1) mx = fmaxf(mx, __shfl_xor(mx, d));
      float sum = 0.f;
      #pragma unroll
      for (int nt=0; nt<4; nt++){
        float p = mk[nt] ? 0.f : __expf(sv[nt]-mx);
        sv[nt] = p; sum += p;
      }
      for (int d=1; d<16; d<<=1) sum += __shfl_xor(sum, d);
      rsi[mt][r] = sum > 0.f ? 1.f/sum : 0.f;   // all-masked row -> 0
      #pragma unroll
      for (int nt=0; nt<4; nt++)
        p_s[w][SWZ(arow, nt*16+lr, 64, 7)] = (short)f2bf(sv[nt]);
    }
  }
  // att = (p @ v) * rsi (8 MFMAs)
  ffrag o[2][2];
  #pragma unroll
  for (int mt=0;mt<2;mt++)
    #pragma unroll
    for (int nt=0;nt<2;nt++) o[mt][nt]=fzero();
  #pragma unroll
  for (int kk=0; kk<2; kk++){
    int kc = kk*32 + ko*8;
    bfrag pa0 = *(const bfrag*)(p_s[w]  + SWZ(lr,    kc, 64, 7));
    bfrag pa1 = *(const bfrag*)(p_s[w]  + SWZ(16+lr, kc, 64, 7));
    bfrag bv0 = *(const bfrag*)(vT_s[w] + SWZ(lr,    kc, 64, 7));
    bfrag bv1 = *(const bfrag*)(vT_s[w] + SWZ(16+lr, kc, 64, 7));
    o[0][0]=MFMA(pa0,bv0,o[0][0]); o[0][1]=MFMA(pa0,bv1,o[0][1]);
    o[1][0]=MFMA(pa1,bv0,o[1][0]); o[1][1]=MFMA(pa1,bv1,o[1][1]);
  }
  #pragma unroll
  for (int mt=0; mt<2; mt++)
    #pragma unroll
    for (int nt=0; nt<2; nt++)
      #pragma unroll
      for (int r=0; r<4; r++){
        int a = mt*16 + ko*4 + r;
        attB[((long)b*32 + a)*256 + h*32 + nt*16 + lr] = (short)f2bf(o[mt][nt][r]*rsi[mt][r]);
      }
}

// ---------------- K3: GRU cell ----------------
__global__ __launch_bounds__(512) void k3_gru(const short* __restrict__ attB,
    const short* __restrict__ h0B, const short* __restrict__ wih, const short* __restrict__ whh,
    const float* __restrict__ h0f, const float* __restrict__ b_ih, const float* __restrict__ b_hh,
    const void* __restrict__ scen, float* __restrict__ hout, const int* __restrict__ flagp){
  __shared__ __align__(16) short wih_s[3*32*256];
  __shared__ __align__(16) short whh_s[3*32*256];
  int t = threadIdx.x;
  int mblk = blockIdx.x >> 3, jblk = blockIdx.x & 7;
  long R0 = (long)mblk * 128; int j0 = jblk*32;
  int mflag = *flagp;
  for (int i=0;i<12;i++){
    int c = t + i*512;
    int slab = c >> 10; int cm = c & 1023; int row = cm >> 5; int cc = (cm & 31)*8;
    const short* src; short* dst;
    if (slab < 3){ src = wih + (((long)slab*256 + j0 + row)*256 + cc); dst = wih_s + slab*8192; }
    else         { src = whh + (((long)(slab-3)*256 + j0 + row)*256 + cc); dst = whh_s + (slab-3)*8192; }
    *(bfrag*)(dst + SWZ(row, cc, 256, 7)) = *(const bfrag*)src;
  }
  __syncthreads();
  int lane = t & 63, w = t >> 6, lr = lane & 15, ko = lane >> 4;
  long abase = (R0 + w*16 + lr) * 256L;
  ffrag acc[6][2];
  #pragma unroll
  for (int g=0;g<6;g++) for (int nt=0;nt<2;nt++) acc[g][nt] = fzero();
  bfrag a_att = *(const bfrag*)(attB + abase + ko*8);
  bfrag a_h0  = *(const bfrag*)(h0B  + abase + ko*8);
  for (int ks=0; ks<8; ks++){
    bfrag n_att = a_att, n_h0 = a_h0;
    if (ks < 7){
      int kc = (ks+1)*32 + ko*8;
      n_att = *(const bfrag*)(attB + abase + kc);
      n_h0  = *(const bfrag*)(h0B  + abase + kc);
    }
    int kc = ks*32 + ko*8;
    #pragma unroll
    for (int g=0; g<3; g++){
      #pragma unroll
      for (int nt=0; nt<2; nt++){
        bfrag bi = *(const bfrag*)(wih_s + g*8192 + SWZ(nt*16+lr, kc, 256, 7));
        acc[g][nt] = MFMA(a_att, bi, acc[g][nt]);
      }
      #pragma unroll
      for (int nt=0; nt<2; nt++){
        bfrag bh = *(const bfrag*)(whh_s + g*8192 + SWZ(nt*16+lr, kc, 256, 7));
        acc[3+g][nt] = MFMA(a_h0, bh, acc[3+g][nt]);
      }
    }
    a_att = n_att; a_h0 = n_h0;
  }
  #pragma unroll
  for (int nt=0; nt<2; nt++){
    int j = j0 + nt*16 + lr;
    float bir = b_ih[j],     bhr = b_hh[j];
    float biz = b_ih[256+j], bhz = b_hh[256+j];
    float bin = b_ih[512+j], bhn = b_hh[512+j];
    #pragma unroll
    for (int r=0;r<4;r++){
      long row = R0 + w*16 + ko*4 + r;
      float ir = acc[0][nt][r], iz = acc[1][nt][r], inn = acc[2][nt][r];
      float hr = acc[3][nt][r], hz = acc[4][nt][r], hn = acc[5][nt][r];
      float rr = 1.f/(1.f + __expf(-(ir + hr + bir + bhr)));
      float zz = 1.f/(1.f + __expf(-(iz + hz + biz + bhz)));
      float ag = inn + bin + rr*(hn + bhn);
      float nn = 2.f/(1.f + __expf(-2.f*ag)) - 1.f;   // tanh
      float h0v = h0f[row*256 + j];
      float hv = (1.f - zz)*nn + zz*h0v;
      if (getmask(scen, row, mflag)) hv = 0.f;
      hout[row*256 + j] = hv;
    }
  }
}

// ---------------- K4: q_out = h @ out_w^T + out_b (masked) ----------------
__global__ __launch_bounds__(512) void k4_out(const float* __restrict__ hout,
    const short* __restrict__ ow, const float* __restrict__ out_b,
    const void* __restrict__ scen, float* __restrict__ qout, const int* __restrict__ flagp){
  __shared__ __align__(16) short ow_s[32*256];
  int t = threadIdx.x; long R0 = (long)blockIdx.x * 256;
  int mflag = *flagp;
  for (int i=0;i<2;i++){
    int c = t + i*512; int row = c >> 5; int cc = (c & 31)*8;
    *(bfrag*)(ow_s + SWZ(row, cc, 256, 7)) = *(const bfrag*)(ow + row*256 + cc);
  }
  __syncthreads();
  int lane = t&63, w = t>>6, lr = lane&15, ko = lane>>4;
  ffrag acc[2][2];
  #pragma unroll
  for (int a=0;a<2;a++) for (int bq=0;bq<2;bq++) acc[a][bq]=fzero();
  for (int ks=0; ks<8; ks++){
    int kc = ks*32 + ko*8;
    #pragma unroll
    for (int mi=0; mi<2; mi++){
      long row = R0 + (w*2+mi)*16 + lr;
      const float* hp = hout + row*256 + kc;
      float4 f0 = *(const float4*)hp; float4 f1 = *(const float4*)(hp+4);
      bfrag a;
      a[0]=(short)f2bf(f0.x); a[1]=(short)f2bf(f0.y); a[2]=(short)f2bf(f0.z); a[3]=(short)f2bf(f0.w);
      a[4]=(short)f2bf(f1.x); a[5]=(short)f2bf(f1.y); a[6]=(short)f2bf(f1.z); a[7]=(short)f2bf(f1.w);
      #pragma unroll
      for (int nt=0; nt<2; nt++){
        bfrag bb = *(const bfrag*)(ow_s + SWZ(nt*16+lr, kc, 256, 7));
        acc[mi][nt] = MFMA(a, bb, acc[mi][nt]);
      }
    }
  }
  #pragma unroll
  for (int mi=0;mi<2;mi++)
    #pragma unroll
    for (int nt=0;nt<2;nt++){
      int col = nt*16 + lr;
      float ob = out_b[col];
      #pragma unroll
      for (int r=0;r<4;r++){
        long row = R0 + (w*2+mi)*16 + ko*4 + r;
        float qv = acc[mi][nt][r] + ob;
        if (getmask(scen, row, mflag)) qv = 0.f;
        qout[row*32 + col] = qv;
      }
    }
}

extern "C" void kernel_launch(void* const* d_in, const int* in_sizes, int n_in,
                              void* d_out, int out_size, void* d_ws, size_t ws_size,
                              hipStream_t stream){
  const float* inputs = (const float*)d_in[0];
  const float* hidden = (const float*)d_in[1];
  const float* fc1_w  = (const float*)d_in[2];
  const float* fc1_b  = (const float*)d_in[3];
  const float* q_w    = (const float*)d_in[4];
  const float* q_b    = (const float*)d_in[5];
  const float* k_w    = (const float*)d_in[6];
  const float* k_b    = (const float*)d_in[7];
  const float* v_w    = (const float*)d_in[8];
  const float* v_b    = (const float*)d_in[9];
  const float* w_ih   = (const float*)d_in[10];
  const float* w_hh   = (const float*)d_in[11];
  const float* b_ih   = (const float*)d_in[12];
  const float* b_hh   = (const float*)d_in[13];
  const float* out_w  = (const float*)d_in[14];
  const float* out_b  = (const float*)d_in[15];
  const void* obsm    = d_in[16];
  const void* scen    = d_in[17];
  (void)in_sizes; (void)n_in; (void)out_size;
  if ((long)ws_size < WS_NEED_BYTES) return;
  short* ws = (short*)d_ws;
  const int* flagp = (const int*)d_ws;
  float* qout = (float*)d_out;
  float* hout = qout + 4194304;
  // chunk scratch (dead regions of d_out until K3/K4 write them):
  short* qCs = (short*)qout;             // 1024*32*256 shorts = qout region exactly
  short* kCs = (short*)hout;             // 1024*64*256 shorts
  short* vCs = kCs + 16777216L;          // 1024*64*256 shorts (first half of hout total)
  short* attB = ws + OFF_ATTB;
  short* h0B  = ws + OFF_H0B;

  hipLaunchKernelGGL(k0_prep, dim3(4096), dim3(256), 0, stream,
      fc1_w, q_w, k_w, v_w, w_ih, w_hh, out_w, hidden, obsm, ws);
  for (int c=0; c<4; c++){
    hipLaunchKernelGGL(k1_fqkv, dim3(512), dim3(512), 0, stream,
        inputs, ws + OFF_FC1, fc1_b, ws + OFF_QW, ws + OFF_KW, ws + OFF_VW,
        q_b, k_b, v_b, qCs, kCs, vCs, c);
    hipLaunchKernelGGL(k2_attn, dim3(1024), dim3(512), 0, stream,
        qCs, kCs, vCs, obsm, attB, flagp, c);
  }
  hipLaunchKernelGGL(k3_gru, dim3(8192), dim3(512), 0, stream,
      attB, h0B, ws + OFF_WIH, ws + OFF_WHH, hidden, b_ih, b_hh, scen, hout, flagp);
  hipLaunchKernelGGL(k4_out, dim3(512), dim3(512), 0, stream,
      hout, ws + OFF_OW, out_b, scen, qout, flagp);
}